// Round 4
// baseline (186.605 us; speedup 1.0000x reference)
//
#include <hip/hip_runtime.h>
#include <hip/hip_bf16.h>
#include <stdint.h>

// QuantizedConv2d int8: x (32,128,56,56), w (256,128,3,3), pad 1, stride 1.
// Implicit GEMM on v_mfma_i32_32x32x32_i8. M=out-ch, N=pixels, K=9*128=1152.
// R13: T3+T4 counted-vmcnt tap pipeline. lx (6 rows, XOR swizzle) staged once;
// lw = 3 x 16 KB rotating buffers, tap t+2 prefetched at tap t. Per tap:
// s_waitcnt vmcnt(2) [vmcnt(0) only at tap 8] -> raw s_barrier -> issue
// prefetch -> 16 MFMA. No full vmcnt drain in the main loop (m233's 72%
// 2-phase tax was the R9-R12 invariant). 95.7 KB LDS -> 1 block/CU, 8 waves
// (2/SIMD) -- the m201-proven regime. T5 setprio around each MFMA cluster.

#define NB   32
#define CIN  128
#define HO   56
#define WO   56
#define KOUT 256
#define HP   58
#define ROWB (HP * CIN)          // 7424 bytes per padded row

typedef int v4i  __attribute__((ext_vector_type(4)));
typedef int v16i __attribute__((ext_vector_type(16)));

static __device__ __forceinline__ void gload_lds16(const int8_t* g, int8_t* l) {
  __builtin_amdgcn_global_load_lds(
      (const __attribute__((address_space(1))) void*)g,
      (__attribute__((address_space(3))) void*)l, 16, 0, 0);
}

// ---------------- pack x: NCHW int32 -> padded NHWC int8 (int4 reads) --------
__global__ __launch_bounds__(256) void pack_x_kernel(const int* __restrict__ x,
                                                     int8_t* __restrict__ xp) {
  __shared__ int t32[128][57];       // 29,184 B, stride 57 to break conflicts
  const int tid = threadIdx.x;
  const int r = blockIdx.x;          // padded row 0..57
  const int n = blockIdx.y;
  const bool interior = (r >= 1) && (r <= HO);

  if (interior) {
    const int h = r - 1;
    const int* xrow = x + ((size_t)(n * CIN) * HO + h) * WO;  // c stride = 3136 ints
    #pragma unroll
    for (int it = 0; it < 7; ++it) {
      const int j = it * 256 + tid;  // < 1792 = 128 c x 14 w-quads
      const int c = j / 14;
      const int w4 = j - c * 14;
      const int4 v = *reinterpret_cast<const int4*>(xrow + c * 3136 + w4 * 4);
      t32[c][w4 * 4 + 0] = v.x;
      t32[c][w4 * 4 + 1] = v.y;
      t32[c][w4 * 4 + 2] = v.z;
      t32[c][w4 * 4 + 3] = v.w;
    }
  }
  __syncthreads();
  #pragma unroll
  for (int it = 0; it < 8; ++it) {
    const int i = it * 256 + tid;
    if (i < HP * 32) {
      const int w = i >> 5;          // padded col 0..57
      const int c4 = i & 31;
      int vv = 0;
      if (interior && w >= 1 && w <= WO) {
        const int b0 = t32[c4 * 4 + 0][w - 1] & 0xff;
        const int b1 = t32[c4 * 4 + 1][w - 1] & 0xff;
        const int b2 = t32[c4 * 4 + 2][w - 1] & 0xff;
        const int b3 = t32[c4 * 4 + 3][w - 1];
        vv = b0 | (b1 << 8) | (b2 << 16) | (b3 << 24);
      }
      *reinterpret_cast<int*>(xp + ((size_t)(n * HP + r) * HP + w) * CIN + c4 * 4) = vv;
    }
  }
}

// ---- pack w: OIHW int32 -> [ktb(2)][tap(9)][cc(8)][ch(128)] 16B chunks ------
__global__ __launch_bounds__(256) void pack_w_kernel(const int* __restrict__ wgt,
                                                     int8_t* __restrict__ wq) {
  const int wid = blockIdx.x * 256 + threadIdx.x;   // 0..73727 int32 words
  const int wi = wid & 3;
  const int ci = wid >> 2;                          // chunk 0..18431
  const int ktb = ci / 9216;                        // 9216 = 9*8*128
  const int r  = ci - ktb * 9216;
  const int tap = r >> 10;                          // 1024 = 8*128
  const int r2  = r & 1023;
  const int cc  = r2 >> 7;
  const int ch  = r2 & 127;
  const int k_global = ktb * 128 + ch;
  const int cin0 = cc * 16 + wi * 4;
  const int base = (k_global * CIN + cin0) * 9 + tap;  // OIHW, 3x3=9 taps
  const int v0 = wgt[base];
  const int v1 = wgt[base + 9];
  const int v2 = wgt[base + 18];
  const int v3 = wgt[base + 27];
  reinterpret_cast<int*>(wq)[wid] =
      (v0 & 0xff) | ((v1 & 0xff) << 8) | ((v2 & 0xff) << 16) | (v3 << 24);
}

// ------- conv: counted-vmcnt tap pipeline, 3-deep lw, 1 barrier/tap ---------
// grid (14 rg, 32 n, 2 ktb) = 896 blocks, 512 threads = 8 waves.
// Block: 128 out-ch x 4 output rows. Wave (wr=row 0..3, wh=ch-half 0..1):
// 64 ch x 64 px, acc[2][2] = 64 VGPR. Per ks: 2 A + 2 B LDS b128 -> 4 MFMA.
__global__ __launch_bounds__(512, 2) void conv_kernel(const int8_t* __restrict__ xp,
                                                      const int8_t* __restrict__ wq,
                                                      const int* __restrict__ bias,
                                                      const float* __restrict__ wscale,
                                                      int* __restrict__ out) {
  __shared__ __align__(16) int8_t lw0[8 * 128 * 16];          // 16,384 B
  __shared__ __align__(16) int8_t lw1[8 * 128 * 16];
  __shared__ __align__(16) int8_t lw2[8 * 128 * 16];
  __shared__ __align__(16) int8_t lx[(6 * HP + 8) * 8 * 16];  // 45,568 B (+pad)
  __shared__ int   bsh[128];
  __shared__ float ssh[128];

  const int tid = threadIdx.x;
  const int rg = blockIdx.x;           // row group 0..13
  const int n_img = blockIdx.y;
  const int ktb = blockIdx.z;          // 128-ch slice, slowest -> L2 reuse of xp
  const int h0 = rg * 4;

  const int lane = tid & 63;
  const int wid = tid >> 6;            // wave 0..7
  const int wr = wid & 3;              // output row
  const int wh = wid >> 2;             // 64-ch half
  const int p0 = lane & 31;
  const int half = lane >> 5;

  const int8_t* xg = xp + ((size_t)(n_img * HP) + h0) * ROWB;
  const int8_t* wqt = wq + (size_t)ktb * (9 * 16384);

  // ---- stage pixels: 6 padded rows = 2784 chunks, XOR swizzle in source ----
  #pragma unroll
  for (int it = 0; it < 6; ++it) {
    const int i = it * 512 + tid;
    if (i < 6 * HP * 8) {
      const int pf = i >> 3;
      const int cc = (i & 7) ^ (pf & 7);
      gload_lds16(xg + pf * CIN + (cc << 4), lx + i * 16);
    }
  }
  // ---- stage weights taps 0 and 1 ----
  gload_lds16(wqt + tid * 16,                   lw0 + tid * 16);
  gload_lds16(wqt + (512 + tid) * 16,           lw0 + (512 + tid) * 16);
  gload_lds16(wqt + 16384 + tid * 16,           lw1 + tid * 16);
  gload_lds16(wqt + 16384 + (512 + tid) * 16,   lw1 + (512 + tid) * 16);
  if (tid < 128) {
    const int ch = ktb * 128 + tid;
    bsh[tid] = bias[ch];
    ssh[tid] = (0.02f * wscale[ch]) / 0.05f;   // IN_SCALE * ws / OUT_SCALE
  }
  __syncthreads();                     // prologue: one full drain (only one)

  v16i acc[2][2];                      // [mt: 32-ch tile][nt: 32-px tile]
  #pragma unroll
  for (int mt = 0; mt < 2; ++mt)
    #pragma unroll
    for (int nt = 0; nt < 2; ++nt)
      #pragma unroll
      for (int e = 0; e < 16; ++e) acc[mt][nt][e] = 0;

  const int chb = wh * 64;             // this wave's 64-ch half

  #pragma unroll
  for (int tap = 0; tap < 9; ++tap) {
    // Counted wait: retire the loads for buffer tap%3 (issued at tap-2; only
    // tap-1's 2 loads can be newer). Full drain only at the final tap.
    if (tap < 8) {
      asm volatile("s_waitcnt vmcnt(2)" ::: "memory");
    } else {
      asm volatile("s_waitcnt vmcnt(0)" ::: "memory");
    }
    // Barrier also proves all waves finished READING buffer (tap+2)%3 ==
    // (tap-1)%3 at tap-1, so it is safe to overwrite below.
    __builtin_amdgcn_s_barrier();
    if (tap < 7) {
      const int8_t* wsrc = wqt + (tap + 2) * 16384;
      int8_t* ldst = ((tap + 2) % 3 == 0) ? lw0 : (((tap + 2) % 3 == 1) ? lw1 : lw2);
      gload_lds16(wsrc + tid * 16,         ldst + tid * 16);
      gload_lds16(wsrc + (512 + tid) * 16, ldst + (512 + tid) * 16);
    }
    const int kh = (tap >= 3) + (tap >= 6);
    const int kw = tap - 3 * kh;
    const int8_t* lwt = (tap % 3 == 0) ? lw0 : ((tap % 3 == 1) ? lw1 : lw2);
    const int pfb = (wr + kh) * HP + kw;
    #pragma unroll
    for (int ks = 0; ks < 4; ++ks) {
      const int cch = 2 * ks + half;             // k-chunk for this lane
      const v4i a0 = *reinterpret_cast<const v4i*>(lwt + cch * 2048 + (chb + p0) * 16);
      const v4i a1 = *reinterpret_cast<const v4i*>(lwt + cch * 2048 + (chb + 32 + p0) * 16);
      const int pf0 = pfb + p0;
      const int pf1 = pfb + 32 + p0;
      const v4i b0 = *reinterpret_cast<const v4i*>(lx + pf0 * CIN + ((cch ^ (pf0 & 7)) << 4));
      const v4i b1 = *reinterpret_cast<const v4i*>(lx + pf1 * CIN + ((cch ^ (pf1 & 7)) << 4));
      // edge reads (col>57) land in the lx pad; they feed only masked w>=56.
      __builtin_amdgcn_s_setprio(1);
      acc[0][0] = __builtin_amdgcn_mfma_i32_32x32x32_i8(a0, b0, acc[0][0], 0, 0, 0);
      acc[1][0] = __builtin_amdgcn_mfma_i32_32x32x32_i8(a1, b0, acc[1][0], 0, 0, 0);
      acc[0][1] = __builtin_amdgcn_mfma_i32_32x32x32_i8(a0, b1, acc[0][1], 0, 0, 0);
      acc[1][1] = __builtin_amdgcn_mfma_i32_32x32x32_i8(a1, b1, acc[1][1], 0, 0, 0);
      __builtin_amdgcn_s_setprio(0);
    }
  }

  // ---- epilogue: D row = ch = mt*32 + (r&3)+8*(r>>2)+4*half, col = pixel ----
  const int h = h0 + wr;
  #pragma unroll
  for (int mt = 0; mt < 2; ++mt) {
    #pragma unroll
    for (int r = 0; r < 16; ++r) {
      const int cl = chb + mt * 32 + (r & 3) + 8 * (r >> 2) + 4 * half;
      const int bi = bsh[cl];
      const float sc = ssh[cl];
      int* ob = out + (((size_t)(n_img * KOUT + ktb * 128 + cl)) * HO + h) * WO;
      #pragma unroll
      for (int nt = 0; nt < 2; ++nt) {
        const int w = nt * 32 + p0;
        if (w < WO) {
          float v = (float)(acc[mt][nt][r] + bi) * sc;
          v = rintf(v);                          // round-half-even == jnp.round
          v = fminf(fmaxf(v, -128.0f), 127.0f);
          ob[w] = (int)v;
        }
      }
    }
  }
}

extern "C" void kernel_launch(void* const* d_in, const int* in_sizes, int n_in,
                              void* d_out, int out_size, void* d_ws, size_t ws_size,
                              hipStream_t stream) {
  const int* x = (const int*)d_in[0];
  const int* wgt = (const int*)d_in[1];
  const int* bias = (const int*)d_in[2];
  const float* wscale = (const float*)d_in[3];
  int* out = (int*)d_out;

  int8_t* xp = (int8_t*)d_ws;                               // 13,780,992 B
  int8_t* wq = (int8_t*)d_ws + (size_t)NB * HP * ROWB;      // 294,912 B

  pack_x_kernel<<<dim3(HP, NB), 256, 0, stream>>>(x, xp);
  pack_w_kernel<<<288, 256, 0, stream>>>(wgt, wq);
  conv_kernel<<<dim3(14, 32, 2), 512, 0, stream>>>(xp, wq, bias, wscale, out);
}

// Round 5
// 186.267 us; speedup vs baseline: 1.0018x; 1.0018x over previous
//
#include <hip/hip_runtime.h>
#include <hip/hip_bf16.h>
#include <stdint.h>

// QuantizedConv2d int8: x (32,128,56,56), w (256,128,3,3), pad 1, stride 1.
// Implicit GEMM on v_mfma_i32_32x32x32_i8. M=out-ch, N=pixels, K=9*128=1152.
// R14: ZERO-BARRIER K-loop at 16 waves/CU. Wave = 32ch x 64px (acc 2x16).
// A fragments loaded per-(tap,ks) straight from packed wq in L2 (73 KB/slice,
// 1 dwordx4/lane, used twice) -- no weight LDS, no staging, no K-loop sync.
// B from LDS (4 padded x-rows, 30.7 KB, XOR swizzle) staged once at prologue.
// 4 blocks/CU x 4 waves = 16 free-running waves (4/SIMD): TLP hides ds_read
// and L2 latency the way R9-R13's 2-phase/counted schedules never did.
// Pipes/CU over the run: MFMA 15.4 us, LDS-B ~23 us, VMEM-A ~15 us.

#define NB   32
#define CIN  128
#define HO   56
#define WO   56
#define KOUT 256
#define HP   58
#define ROWB (HP * CIN)          // 7424 bytes per padded row

typedef int v4i  __attribute__((ext_vector_type(4)));
typedef int v16i __attribute__((ext_vector_type(16)));

static __device__ __forceinline__ void gload_lds16(const int8_t* g, int8_t* l) {
  __builtin_amdgcn_global_load_lds(
      (const __attribute__((address_space(1))) void*)g,
      (__attribute__((address_space(3))) void*)l, 16, 0, 0);
}

// ---------------- pack x: NCHW int32 -> padded NHWC int8 (int4 reads) --------
__global__ __launch_bounds__(256) void pack_x_kernel(const int* __restrict__ x,
                                                     int8_t* __restrict__ xp) {
  __shared__ int t32[128][57];       // 29,184 B, stride 57 to break conflicts
  const int tid = threadIdx.x;
  const int r = blockIdx.x;          // padded row 0..57
  const int n = blockIdx.y;
  const bool interior = (r >= 1) && (r <= HO);

  if (interior) {
    const int h = r - 1;
    const int* xrow = x + ((size_t)(n * CIN) * HO + h) * WO;  // c stride = 3136 ints
    #pragma unroll
    for (int it = 0; it < 7; ++it) {
      const int j = it * 256 + tid;  // < 1792 = 128 c x 14 w-quads
      const int c = j / 14;
      const int w4 = j - c * 14;
      const int4 v = *reinterpret_cast<const int4*>(xrow + c * 3136 + w4 * 4);
      t32[c][w4 * 4 + 0] = v.x;
      t32[c][w4 * 4 + 1] = v.y;
      t32[c][w4 * 4 + 2] = v.z;
      t32[c][w4 * 4 + 3] = v.w;
    }
  }
  __syncthreads();
  #pragma unroll
  for (int it = 0; it < 8; ++it) {
    const int i = it * 256 + tid;
    if (i < HP * 32) {
      const int w = i >> 5;          // padded col 0..57
      const int c4 = i & 31;
      int vv = 0;
      if (interior && w >= 1 && w <= WO) {
        const int b0 = t32[c4 * 4 + 0][w - 1] & 0xff;
        const int b1 = t32[c4 * 4 + 1][w - 1] & 0xff;
        const int b2 = t32[c4 * 4 + 2][w - 1] & 0xff;
        const int b3 = t32[c4 * 4 + 3][w - 1];
        vv = b0 | (b1 << 8) | (b2 << 16) | (b3 << 24);
      }
      *reinterpret_cast<int*>(xp + ((size_t)(n * HP + r) * HP + w) * CIN + c4 * 4) = vv;
    }
  }
}

// ------ pack w: OIHW int32 -> [kt(4)][tap(9)][cc(8)][ch(64)] 16B chunks ------
__global__ __launch_bounds__(256) void pack_w_kernel(const int* __restrict__ wgt,
                                                     int8_t* __restrict__ wq) {
  const int wid = blockIdx.x * 256 + threadIdx.x;   // 0..73727 int32 words
  const int wi = wid & 3;
  const int ci = wid >> 2;                          // chunk 0..18431
  const int kt = ci / 4608;                         // 4608 = 9*8*64
  const int r  = ci - kt * 4608;
  const int tap = r >> 9;                           // 512 = 8*64
  const int r2  = r & 511;
  const int cc  = r2 >> 6;
  const int ch  = r2 & 63;
  const int k_global = kt * 64 + ch;
  const int cin0 = cc * 16 + wi * 4;
  const int base = (k_global * CIN + cin0) * 9 + tap;  // OIHW, 3x3=9 taps
  const int v0 = wgt[base];
  const int v1 = wgt[base + 9];
  const int v2 = wgt[base + 18];
  const int v3 = wgt[base + 27];
  reinterpret_cast<int*>(wq)[wid] =
      (v0 & 0xff) | ((v1 & 0xff) << 8) | ((v2 & 0xff) << 16) | (v3 << 24);
}

// -------- conv: zero-barrier K-loop, A from L2 per-use, B from LDS ---------
// grid (28 rg, 32 n, 4 kt) = 3584 blocks, 256 threads = 4 waves.
// Block: 64 out-ch x 2 output rows. Wave w: slice = w>>1 (32 ch), wr = w&1.
// Per (tap,ks): 1 global dwordx4 A-frag + 2 LDS b128 B -> 2 MFMAs.
__global__ __launch_bounds__(256, 4) void conv_kernel(const int8_t* __restrict__ xp,
                                                      const int8_t* __restrict__ wq,
                                                      const int* __restrict__ bias,
                                                      const float* __restrict__ wscale,
                                                      int* __restrict__ out) {
  __shared__ __align__(16) int8_t lx[(4 * HP + 8) * 8 * 16];  // 30,720 B (+pad)
  __shared__ int   bsh[64];
  __shared__ float ssh[64];

  const int tid = threadIdx.x;
  const int rg = blockIdx.x;           // row group 0..27 (2 rows each)
  const int n_img = blockIdx.y;
  const int kt = blockIdx.z;           // 64-ch slice
  const int h0 = rg * 2;

  const int lane = tid & 63;
  const int wv = tid >> 6;             // wave 0..3
  const int wr = wv & 1;               // output row 0..1
  const int slice = wv >> 1;           // 32-ch slice 0..1
  const int p0 = lane & 31;
  const int half = lane >> 5;

  const int8_t* xg = xp + ((size_t)(n_img * HP) + h0) * ROWB;
  const int8_t* wqt = wq + (size_t)kt * 73728 + (slice * 32 + p0) * 16;

  // ---- stage pixels: 4 padded rows = 1856 chunks, XOR swizzle in source ----
  #pragma unroll
  for (int it = 0; it < 8; ++it) {
    const int i = it * 256 + tid;
    if (i < 4 * HP * 8) {
      const int pf = i >> 3;
      const int cc = (i & 7) ^ (pf & 7);
      gload_lds16(xg + pf * CIN + (cc << 4), lx + i * 16);
    }
  }
  if (tid < 64) {
    const int ch = kt * 64 + tid;
    bsh[tid] = bias[ch];
    ssh[tid] = (0.02f * wscale[ch]) / 0.05f;   // IN_SCALE * ws / OUT_SCALE
  }
  __syncthreads();                     // the ONLY barrier in this kernel

  v16i acc[2];                         // [nt: 32-px tile], 32 ch x 64 px
  #pragma unroll
  for (int nt = 0; nt < 2; ++nt)
    #pragma unroll
    for (int e = 0; e < 16; ++e) acc[nt][e] = 0;

  #pragma unroll
  for (int tap = 0; tap < 9; ++tap) {
    const int kh = (tap >= 3) + (tap >= 6);
    const int kw = tap - 3 * kh;
    const int pfb = (wr + kh) * HP + kw;
    #pragma unroll
    for (int ks = 0; ks < 4; ++ks) {
      const int cch = 2 * ks + half;             // k-chunk for this lane
      // A fragment straight from L2-resident packed weights (no LDS, no sync)
      const v4i a = *reinterpret_cast<const v4i*>(wqt + tap * 8192 + cch * 1024);
      const int pf0 = pfb + p0;
      const int pf1 = pfb + 32 + p0;
      const v4i b0 = *reinterpret_cast<const v4i*>(lx + pf0 * CIN + ((cch ^ (pf0 & 7)) << 4));
      const v4i b1 = *reinterpret_cast<const v4i*>(lx + pf1 * CIN + ((cch ^ (pf1 & 7)) << 4));
      // edge reads (pf > 4*58-1) land in the lx pad; they feed only masked w>=56.
      acc[0] = __builtin_amdgcn_mfma_i32_32x32x32_i8(a, b0, acc[0], 0, 0, 0);
      acc[1] = __builtin_amdgcn_mfma_i32_32x32x32_i8(a, b1, acc[1], 0, 0, 0);
    }
  }

  // ---- epilogue: D row = ch = (r&3)+8*(r>>2)+4*half, col = pixel ----
  const int h = h0 + wr;
  #pragma unroll
  for (int r = 0; r < 16; ++r) {
    const int cl = slice * 32 + (r & 3) + 8 * (r >> 2) + 4 * half;
    const int bi = bsh[cl];
    const float sc = ssh[cl];
    int* ob = out + (((size_t)(n_img * KOUT + kt * 64 + cl)) * HO + h) * WO;
    #pragma unroll
    for (int nt = 0; nt < 2; ++nt) {
      const int w = nt * 32 + p0;
      if (w < WO) {
        float v = (float)(acc[nt][r] + bi) * sc;
        v = rintf(v);                          // round-half-even == jnp.round
        v = fminf(fmaxf(v, -128.0f), 127.0f);
        ob[w] = (int)v;
      }
    }
  }
}

extern "C" void kernel_launch(void* const* d_in, const int* in_sizes, int n_in,
                              void* d_out, int out_size, void* d_ws, size_t ws_size,
                              hipStream_t stream) {
  const int* x = (const int*)d_in[0];
  const int* wgt = (const int*)d_in[1];
  const int* bias = (const int*)d_in[2];
  const float* wscale = (const float*)d_in[3];
  int* out = (int*)d_out;

  int8_t* xp = (int8_t*)d_ws;                               // 13,780,992 B
  int8_t* wq = (int8_t*)d_ws + (size_t)NB * HP * ROWB;      // 294,912 B

  pack_x_kernel<<<dim3(HP, NB), 256, 0, stream>>>(x, xp);
  pack_w_kernel<<<288, 256, 0, stream>>>(wgt, wq);
  conv_kernel<<<dim3(28, 32, 4), 256, 0, stream>>>(xp, wq, bias, wscale, out);
}

// Round 6
// 184.519 us; speedup vs baseline: 1.0113x; 1.0095x over previous
//
#include <hip/hip_runtime.h>
#include <hip/hip_bf16.h>
#include <stdint.h>

// QuantizedConv2d int8: x (32,128,56,56), w (256,128,3,3), pad 1, stride 1.
// Implicit GEMM on v_mfma_i32_32x32x32_i8. M=out-ch, N=pixels, K=9*128=1152.
// R15: faithful m201-style phase schedule on R12's geometry. 2 phases/tap:
// {issue prefetch -> vmcnt(2) -> 8 ds_read -> s_barrier -> lgkmcnt(0) ->
//  setprio(1) -> 8 MFMA -> setprio(0) -> s_barrier}. Counted vmcnt only in
// phase A; NEVER vmcnt(0) in the main loop (m218: counted-vs-drain0 was
// +38-73%; R13's coarse variant was m196's proven-negative arm). 8 frag regs
// live per phase keeps VGPR<=128 -> 2 blocks x 8 waves = 16 waves/CU; the two
// independent blocks' LDS-burst and MFMA-burst phases interleave.
// LDS 79,360 B: lw 2x16 KB (per-tap dbuf) + lx 44.5 KB (6 rows, XOR swizzle).

#define NB   32
#define CIN  128
#define HO   56
#define WO   56
#define KOUT 256
#define HP   58
#define ROWB (HP * CIN)          // 7424 bytes per padded row

typedef int v4i  __attribute__((ext_vector_type(4)));
typedef int v16i __attribute__((ext_vector_type(16)));

static __device__ __forceinline__ void gload_lds16(const int8_t* g, int8_t* l) {
  __builtin_amdgcn_global_load_lds(
      (const __attribute__((address_space(1))) void*)g,
      (__attribute__((address_space(3))) void*)l, 16, 0, 0);
}

// ---------------- pack x: NCHW int32 -> padded NHWC int8 (int4 reads) --------
__global__ __launch_bounds__(256) void pack_x_kernel(const int* __restrict__ x,
                                                     int8_t* __restrict__ xp) {
  __shared__ int t32[128][57];       // 29,184 B, stride 57 to break conflicts
  const int tid = threadIdx.x;
  const int r = blockIdx.x;          // padded row 0..57
  const int n = blockIdx.y;
  const bool interior = (r >= 1) && (r <= HO);

  if (interior) {
    const int h = r - 1;
    const int* xrow = x + ((size_t)(n * CIN) * HO + h) * WO;  // c stride = 3136 ints
    #pragma unroll
    for (int it = 0; it < 7; ++it) {
      const int j = it * 256 + tid;  // < 1792 = 128 c x 14 w-quads
      const int c = j / 14;
      const int w4 = j - c * 14;
      const int4 v = *reinterpret_cast<const int4*>(xrow + c * 3136 + w4 * 4);
      t32[c][w4 * 4 + 0] = v.x;
      t32[c][w4 * 4 + 1] = v.y;
      t32[c][w4 * 4 + 2] = v.z;
      t32[c][w4 * 4 + 3] = v.w;
    }
  }
  __syncthreads();
  #pragma unroll
  for (int it = 0; it < 8; ++it) {
    const int i = it * 256 + tid;
    if (i < HP * 32) {
      const int w = i >> 5;          // padded col 0..57
      const int c4 = i & 31;
      int vv = 0;
      if (interior && w >= 1 && w <= WO) {
        const int b0 = t32[c4 * 4 + 0][w - 1] & 0xff;
        const int b1 = t32[c4 * 4 + 1][w - 1] & 0xff;
        const int b2 = t32[c4 * 4 + 2][w - 1] & 0xff;
        const int b3 = t32[c4 * 4 + 3][w - 1];
        vv = b0 | (b1 << 8) | (b2 << 16) | (b3 << 24);
      }
      *reinterpret_cast<int*>(xp + ((size_t)(n * HP + r) * HP + w) * CIN + c4 * 4) = vv;
    }
  }
}

// ---- pack w: OIHW int32 -> [ktb(2)][tap(9)][cc(8)][ch(128)] 16B chunks ------
__global__ __launch_bounds__(256) void pack_w_kernel(const int* __restrict__ wgt,
                                                     int8_t* __restrict__ wq) {
  const int wid = blockIdx.x * 256 + threadIdx.x;   // 0..73727 int32 words
  const int wi = wid & 3;
  const int ci = wid >> 2;                          // chunk 0..18431
  const int ktb = ci / 9216;                        // 9216 = 9*8*128
  const int r  = ci - ktb * 9216;
  const int tap = r >> 10;                          // 1024 = 8*128
  const int r2  = r & 1023;
  const int cc  = r2 >> 7;
  const int ch  = r2 & 127;
  const int k_global = ktb * 128 + ch;
  const int cin0 = cc * 16 + wi * 4;
  const int base = (k_global * CIN + cin0) * 9 + tap;  // OIHW, 3x3=9 taps
  const int v0 = wgt[base];
  const int v1 = wgt[base + 9];
  const int v2 = wgt[base + 18];
  const int v3 = wgt[base + 27];
  reinterpret_cast<int*>(wq)[wid] =
      (v0 & 0xff) | ((v1 & 0xff) << 8) | ((v2 & 0xff) << 16) | (v3 << 24);
}

// ---- conv: per-tap dbuf weights, 2 fine phases/tap, counted vmcnt ----------
// grid (14 rg, 32 n, 2 ktb) = 896 blocks, 512 threads = 8 waves.
// Block: 128 out-ch x 4 output rows. Wave (wr=row 0..3, wh=ch-half 0..1):
// 64 ch x 64 px, acc[2][2] = 64 VGPR. Per phase: 8 LDS b128 -> 8 MFMA.
__global__ __launch_bounds__(512, 4) void conv_kernel(const int8_t* __restrict__ xp,
                                                      const int8_t* __restrict__ wq,
                                                      const int* __restrict__ bias,
                                                      const float* __restrict__ wscale,
                                                      int* __restrict__ out) {
  __shared__ __align__(16) int8_t lw[2][8 * 128 * 16];        // 2 x 16,384 B
  __shared__ __align__(16) int8_t lx[(6 * HP + 8) * 8 * 16];  // 45,568 B (+pad)
  __shared__ int   bsh[128];
  __shared__ float ssh[128];

  const int tid = threadIdx.x;
  const int rg = blockIdx.x;           // row group 0..13
  const int n_img = blockIdx.y;
  const int ktb = blockIdx.z;          // 128-ch slice, slowest -> L2 reuse of xp
  const int h0 = rg * 4;

  const int lane = tid & 63;
  const int wvi = tid >> 6;            // wave 0..7
  const int wr = wvi & 3;              // output row
  const int wh = wvi >> 2;             // 64-ch half
  const int p0 = lane & 31;
  const int half = lane >> 5;

  const int8_t* xg = xp + ((size_t)(n_img * HP) + h0) * ROWB;
  const int8_t* wqt = wq + (size_t)ktb * (9 * 16384);

  // ---- stage pixels: 6 padded rows = 2784 chunks, XOR swizzle in source ----
  #pragma unroll
  for (int it = 0; it < 6; ++it) {
    const int i = it * 512 + tid;
    if (i < 6 * HP * 8) {
      const int pf = i >> 3;
      const int cc = (i & 7) ^ (pf & 7);
      gload_lds16(xg + pf * CIN + (cc << 4), lx + i * 16);
    }
  }
  // ---- stage weights tap 0 ----
  gload_lds16(wqt + tid * 16,         lw[0] + tid * 16);
  gload_lds16(wqt + (512 + tid) * 16, lw[0] + (512 + tid) * 16);
  if (tid < 128) {
    const int ch = ktb * 128 + tid;
    bsh[tid] = bias[ch];
    ssh[tid] = (0.02f * wscale[ch]) / 0.05f;   // IN_SCALE * ws / OUT_SCALE
  }
  __syncthreads();                     // prologue: the only full drain

  v16i acc[2][2];                      // [mt: 32-ch tile][nt: 32-px tile]
  #pragma unroll
  for (int mt = 0; mt < 2; ++mt)
    #pragma unroll
    for (int nt = 0; nt < 2; ++nt)
      #pragma unroll
      for (int e = 0; e < 16; ++e) acc[mt][nt][e] = 0;

  const int chb = wh * 64;             // this wave's 64-ch half

  #pragma unroll
  for (int tap = 0; tap < 9; ++tap) {
    const int kh = (tap >= 3) + (tap >= 6);
    const int kw = tap - 3 * kh;
    const int8_t* lwt = lw[tap & 1];             // [cc(8)][ch(128)] chunk-major
    const int pfb = (wr + kh) * HP + kw;

    // ================= phase A: ks 0,1 =================
    // Issue next tap's weight loads (into the buffer last read at tap-1,
    // whose closing barrier already passed), then counted-retire THIS tap's.
    if (tap < 8) {
      const int8_t* wsrc = wqt + (tap + 1) * 16384;
      int8_t* ldst = lw[(tap + 1) & 1];
      gload_lds16(wsrc + tid * 16,         ldst + tid * 16);
      gload_lds16(wsrc + (512 + tid) * 16, ldst + (512 + tid) * 16);
      asm volatile("s_waitcnt vmcnt(2)" ::: "memory");  // retire tap's 2 loads
    } else {
      asm volatile("s_waitcnt vmcnt(0)" ::: "memory");  // last tap: drain
    }
    {
      v4i a0[2], a1[2], b0[2], b1[2];
      #pragma unroll
      for (int ks = 0; ks < 2; ++ks) {
        const int cch = 2 * ks + half;
        a0[ks] = *reinterpret_cast<const v4i*>(lwt + cch * 2048 + (chb + p0) * 16);
        a1[ks] = *reinterpret_cast<const v4i*>(lwt + cch * 2048 + (chb + 32 + p0) * 16);
        const int pf0 = pfb + p0;
        const int pf1 = pfb + 32 + p0;
        b0[ks] = *reinterpret_cast<const v4i*>(lx + pf0 * CIN + ((cch ^ (pf0 & 7)) << 4));
        b1[ks] = *reinterpret_cast<const v4i*>(lx + pf1 * CIN + ((cch ^ (pf1 & 7)) << 4));
      }
      __builtin_amdgcn_s_barrier();
      asm volatile("s_waitcnt lgkmcnt(0)" ::: "memory");
      __builtin_amdgcn_s_setprio(1);
      #pragma unroll
      for (int ks = 0; ks < 2; ++ks) {
        acc[0][0] = __builtin_amdgcn_mfma_i32_32x32x32_i8(a0[ks], b0[ks], acc[0][0], 0, 0, 0);
        acc[1][0] = __builtin_amdgcn_mfma_i32_32x32x32_i8(a1[ks], b0[ks], acc[1][0], 0, 0, 0);
        acc[0][1] = __builtin_amdgcn_mfma_i32_32x32x32_i8(a0[ks], b1[ks], acc[0][1], 0, 0, 0);
        acc[1][1] = __builtin_amdgcn_mfma_i32_32x32x32_i8(a1[ks], b1[ks], acc[1][1], 0, 0, 0);
      }
      __builtin_amdgcn_s_setprio(0);
      __builtin_amdgcn_s_barrier();
    }
    // ================= phase B: ks 2,3 =================
    {
      v4i a0[2], a1[2], b0[2], b1[2];
      #pragma unroll
      for (int ks = 0; ks < 2; ++ks) {
        const int cch = 2 * (ks + 2) + half;
        a0[ks] = *reinterpret_cast<const v4i*>(lwt + cch * 2048 + (chb + p0) * 16);
        a1[ks] = *reinterpret_cast<const v4i*>(lwt + cch * 2048 + (chb + 32 + p0) * 16);
        const int pf0 = pfb + p0;
        const int pf1 = pfb + 32 + p0;
        b0[ks] = *reinterpret_cast<const v4i*>(lx + pf0 * CIN + ((cch ^ (pf0 & 7)) << 4));
        b1[ks] = *reinterpret_cast<const v4i*>(lx + pf1 * CIN + ((cch ^ (pf1 & 7)) << 4));
      }
      __builtin_amdgcn_s_barrier();
      asm volatile("s_waitcnt lgkmcnt(0)" ::: "memory");
      __builtin_amdgcn_s_setprio(1);
      #pragma unroll
      for (int ks = 0; ks < 2; ++ks) {
        acc[0][0] = __builtin_amdgcn_mfma_i32_32x32x32_i8(a0[ks], b0[ks], acc[0][0], 0, 0, 0);
        acc[1][0] = __builtin_amdgcn_mfma_i32_32x32x32_i8(a1[ks], b0[ks], acc[1][0], 0, 0, 0);
        acc[0][1] = __builtin_amdgcn_mfma_i32_32x32x32_i8(a0[ks], b1[ks], acc[0][1], 0, 0, 0);
        acc[1][1] = __builtin_amdgcn_mfma_i32_32x32x32_i8(a1[ks], b1[ks], acc[1][1], 0, 0, 0);
      }
      __builtin_amdgcn_s_setprio(0);
      __builtin_amdgcn_s_barrier();
    }
  }

  // ---- epilogue: D row = ch = mt*32 + (r&3)+8*(r>>2)+4*half, col = pixel ----
  const int h = h0 + wr;
  #pragma unroll
  for (int mt = 0; mt < 2; ++mt) {
    #pragma unroll
    for (int r = 0; r < 16; ++r) {
      const int cl = chb + mt * 32 + (r & 3) + 8 * (r >> 2) + 4 * half;
      const int bi = bsh[cl];
      const float sc = ssh[cl];
      int* ob = out + (((size_t)(n_img * KOUT + ktb * 128 + cl)) * HO + h) * WO;
      #pragma unroll
      for (int nt = 0; nt < 2; ++nt) {
        const int w = nt * 32 + p0;
        if (w < WO) {
          float v = (float)(acc[mt][nt][r] + bi) * sc;
          v = rintf(v);                          // round-half-even == jnp.round
          v = fminf(fmaxf(v, -128.0f), 127.0f);
          ob[w] = (int)v;
        }
      }
    }
  }
}

extern "C" void kernel_launch(void* const* d_in, const int* in_sizes, int n_in,
                              void* d_out, int out_size, void* d_ws, size_t ws_size,
                              hipStream_t stream) {
  const int* x = (const int*)d_in[0];
  const int* wgt = (const int*)d_in[1];
  const int* bias = (const int*)d_in[2];
  const float* wscale = (const float*)d_in[3];
  int* out = (int*)d_out;

  int8_t* xp = (int8_t*)d_ws;                               // 13,780,992 B
  int8_t* wq = (int8_t*)d_ws + (size_t)NB * HP * ROWB;      // 294,912 B

  pack_x_kernel<<<dim3(HP, NB), 256, 0, stream>>>(x, xp);
  pack_w_kernel<<<288, 256, 0, stream>>>(wgt, wq);
  conv_kernel<<<dim3(14, 32, 2), 512, 0, stream>>>(xp, wq, bias, wscale, out);
}